// Round 1
// baseline (603.200 us; speedup 1.0000x reference)
//
#include <hip/hip_runtime.h>
#include <math.h>

#define HW 16384
#define W_ 128

// ---------------------------------------------------------------------------
// 1x1 conv as GEMM: out[n][o][p] = bias[o] + sum_c w[o][c] * in[n][c][p]
// block tile: 128 o x 64 p, 256 threads, each thread 8 o x 4 p, K-chunk 16
// ---------------------------------------------------------------------------
template<int IC>
__global__ __launch_bounds__(256) void conv1x1_kernel(
    const float* __restrict__ in, const float* __restrict__ w,
    const float* __restrict__ bias, float* __restrict__ out,
    long in_nstride, long out_nstride)
{
    __shared__ __align__(16) float ws_s[16][132];
    __shared__ __align__(16) float xs_s[16][68];
    const int tid = threadIdx.x;
    const int to = tid >> 4;   // 0..15, owns o = obase + to*8 + j
    const int tp = tid & 15;   // 0..15, owns p = pbase + tp*4 + i
    const int n = blockIdx.z;
    const int obase = blockIdx.y << 7;
    const int pbase = blockIdx.x << 6;
    const float* inn = in + (long)n * in_nstride;

    float acc[8][4];
#pragma unroll
    for (int j = 0; j < 8; ++j)
#pragma unroll
        for (int i = 0; i < 4; ++i) acc[j][i] = 0.f;

    for (int c0 = 0; c0 < IC; c0 += 16) {
        // stage w tile [16 k][128 o]
#pragma unroll
        for (int it = 0; it < 8; ++it) {
            int idx = (it << 8) + tid;
            int o = idx >> 4, kk = idx & 15;
            ws_s[kk][o] = w[(long)(obase + o) * IC + (c0 + kk)];
        }
        // stage x tile [16 k][64 p]
#pragma unroll
        for (int it = 0; it < 4; ++it) {
            int idx = (it << 8) + tid;
            int kk = idx >> 6, pp = idx & 63;
            xs_s[kk][pp] = inn[(long)(c0 + kk) * HW + pbase + pp];
        }
        __syncthreads();
#pragma unroll
        for (int kk = 0; kk < 16; ++kk) {
            float4 xv = *(const float4*)&xs_s[kk][tp << 2];
            float4 wa = *(const float4*)&ws_s[kk][to << 3];
            float4 wb = *(const float4*)&ws_s[kk][(to << 3) + 4];
            float xr[4] = {xv.x, xv.y, xv.z, xv.w};
            float wr[8] = {wa.x, wa.y, wa.z, wa.w, wb.x, wb.y, wb.z, wb.w};
#pragma unroll
            for (int j = 0; j < 8; ++j)
#pragma unroll
                for (int i = 0; i < 4; ++i)
                    acc[j][i] += wr[j] * xr[i];
        }
        __syncthreads();
    }

    float* outn = out + (long)n * out_nstride + (long)obase * HW + pbase + (tp << 2);
#pragma unroll
    for (int j = 0; j < 8; ++j) {
        int o = (to << 3) + j;
        float b = bias ? bias[obase + o] : 0.f;
        float4 v = make_float4(acc[j][0] + b, acc[j][1] + b, acc[j][2] + b, acc[j][3] + b);
        *(float4*)&outn[(long)o * HW] = v;
    }
}

// ---------------------------------------------------------------------------
// GroupNorm stats: per (n,g) accumulate sum / sumsq with split blocks + atomics
// grid (N*G, SPLIT), block 256. count per group = CG*HW, chunk = count/SPLIT
// ---------------------------------------------------------------------------
__global__ __launch_bounds__(256) void gn_stats_kernel(
    const float* __restrict__ y, float* __restrict__ sums,
    long nstride, int CG, int G, int split_elems)
{
    const int ng = blockIdx.x;
    const int n = ng / G, g = ng % G;
    const float* base = y + (long)n * nstride + (long)g * CG * HW
                        + (long)blockIdx.y * split_elems;
    float s = 0.f, ss = 0.f;
    for (int i = threadIdx.x * 4; i < split_elems; i += 1024) {
        float4 v = *(const float4*)&base[i];
        s  += v.x + v.y + v.z + v.w;
        ss += v.x * v.x + v.y * v.y + v.z * v.z + v.w * v.w;
    }
#pragma unroll
    for (int off = 32; off > 0; off >>= 1) {
        s  += __shfl_down(s, off, 64);
        ss += __shfl_down(ss, off, 64);
    }
    __shared__ float rs[4], rss[4];
    int wave = threadIdx.x >> 6, lane = threadIdx.x & 63;
    if (lane == 0) { rs[wave] = s; rss[wave] = ss; }
    __syncthreads();
    if (threadIdx.x == 0) {
        float S = rs[0] + rs[1] + rs[2] + rs[3];
        float SS = rss[0] + rss[1] + rss[2] + rss[3];
        atomicAdd(&sums[2 * ng], S);
        atomicAdd(&sums[2 * ng + 1], SS);
    }
}

__global__ void gn_final_kernel(const float* __restrict__ sums,
                                float* __restrict__ mu, float* __restrict__ rstd,
                                float cinv)
{
    int i = threadIdx.x;
    if (i < 128) {
        float m = sums[2 * i] * cinv;
        float var = sums[2 * i + 1] * cinv - m * m;
        mu[i] = m;
        rstd[i] = rsqrtf(var + 1e-5f);
    }
}

// normalize + affine + relu, in place. grid (HW/1024, C, N), block 256.
__global__ __launch_bounds__(256) void gn_apply_kernel(
    float* __restrict__ y, const float* __restrict__ mu, const float* __restrict__ rstd,
    const float* __restrict__ gamma, const float* __restrict__ beta,
    long nstride, int CG, int G)
{
    const int n = blockIdx.z, c = blockIdx.y;
    const int ng = n * G + c / CG;
    const float r = rstd[ng];
    const float a = r * gamma[c];
    const float b = beta[c] - mu[ng] * a;
    float* p = y + (long)n * nstride + (long)c * HW + (blockIdx.x << 10) + (threadIdx.x << 2);
    float4 v = *(const float4*)p;
    v.x = fmaxf(v.x * a + b, 0.f);
    v.y = fmaxf(v.y * a + b, 0.f);
    v.z = fmaxf(v.z * a + b, 0.f);
    v.w = fmaxf(v.w * a + b, 0.f);
    *(float4*)p = v;
}

// final: out = relu((y-mu)*rstd*g + b) + x, in place on y(=d_out)
__global__ __launch_bounds__(256) void gn_final_apply_kernel(
    float* __restrict__ y, const float* __restrict__ x,
    const float* __restrict__ mu, const float* __restrict__ rstd,
    const float* __restrict__ gamma, const float* __restrict__ beta,
    long nstride, int CG, int G)
{
    const int n = blockIdx.z, c = blockIdx.y;
    const int ng = n * G + c / CG;
    const float r = rstd[ng];
    const float a = r * gamma[c];
    const float b = beta[c] - mu[ng] * a;
    long off = (long)n * nstride + (long)c * HW + (blockIdx.x << 10) + (threadIdx.x << 2);
    float4 v = *(const float4*)&y[off];
    float4 xv = *(const float4*)&x[off];
    v.x = fmaxf(v.x * a + b, 0.f) + xv.x;
    v.y = fmaxf(v.y * a + b, 0.f) + xv.y;
    v.z = fmaxf(v.z * a + b, 0.f) + xv.z;
    v.w = fmaxf(v.w * a + b, 0.f) + xv.w;
    *(float4*)&y[off] = v;
}

// ---------------------------------------------------------------------------
// cata: 3x3 conv (9 logits) + softmax + weighted 3x3 neighborhood sum.
// xd lives in cat channels 0..127 (n-stride 256*HW); out1 written to 128..255.
// grid (HW/256, N), block 256 (one thread per pixel).
// ---------------------------------------------------------------------------
__global__ __launch_bounds__(256) void cata_kernel(
    float* __restrict__ cat, const float* __restrict__ wc)
{
    __shared__ float wcs[9 * 128 * 9];
    const int tid = threadIdx.x;
    for (int i = tid; i < 9 * 128 * 9; i += 256) wcs[i] = wc[i];
    __syncthreads();

    const int n = blockIdx.y;
    const int p = (blockIdx.x << 8) + tid;
    const int h = p >> 7, w = p & 127;
    const float* xdn = cat + (long)n * 256 * HW;

    float logit[9];
#pragma unroll
    for (int k = 0; k < 9; ++k) logit[k] = 0.f;

    for (int c = 0; c < 128; ++c) {
        const float* xc = xdn + (long)c * HW;
        float nb[9];
#pragma unroll
        for (int di = 0; di < 3; ++di) {
            int hh = h + di - 1;
#pragma unroll
            for (int dj = 0; dj < 3; ++dj) {
                int ww = w + dj - 1;
                bool ok = ((unsigned)hh < 128u) && ((unsigned)ww < 128u);
                nb[di * 3 + dj] = ok ? xc[hh * W_ + ww] : 0.f;
            }
        }
#pragma unroll
        for (int k = 0; k < 9; ++k) {
            const float* wk = &wcs[(k * 128 + c) * 9];
            float s = logit[k];
#pragma unroll
            for (int t = 0; t < 9; ++t) s += wk[t] * nb[t];
            logit[k] = s;
        }
    }
    // softmax over the 9 logits
    float m = logit[0];
#pragma unroll
    for (int k = 1; k < 9; ++k) m = fmaxf(m, logit[k]);
    float sum = 0.f;
#pragma unroll
    for (int k = 0; k < 9; ++k) { logit[k] = expf(logit[k] - m); sum += logit[k]; }
    float inv = 1.f / sum;
#pragma unroll
    for (int k = 0; k < 9; ++k) logit[k] *= inv;

    // weighted neighborhood sum -> out1 (cat channels 128..255)
    float* o1n = cat + (long)n * 256 * HW + (long)128 * HW;
    for (int c = 0; c < 128; ++c) {
        const float* xc = xdn + (long)c * HW;
        float s = 0.f;
#pragma unroll
        for (int di = 0; di < 3; ++di) {
            int hh = h + di - 1;
#pragma unroll
            for (int dj = 0; dj < 3; ++dj) {
                int ww = w + dj - 1;
                bool ok = ((unsigned)hh < 128u) && ((unsigned)ww < 128u);
                float v = ok ? xc[hh * W_ + ww] : 0.f;
                s += logit[di * 3 + dj] * v;
            }
        }
        o1n[(long)c * HW + p] = s;
    }
}

// ---------------------------------------------------------------------------
extern "C" void kernel_launch(void* const* d_in, const int* in_sizes, int n_in,
                              void* d_out, int out_size, void* d_ws, size_t ws_size,
                              hipStream_t stream)
{
    const float* x   = (const float*)d_in[0];
    const float* w1  = (const float*)d_in[1];
    const float* g1  = (const float*)d_in[2];
    const float* b1  = (const float*)d_in[3];
    const float* wc  = (const float*)d_in[4];
    const float* w2  = (const float*)d_in[5];
    const float* bw2 = (const float*)d_in[6];
    const float* g2  = (const float*)d_in[7];
    const float* b2  = (const float*)d_in[8];
    const float* w3  = (const float*)d_in[9];
    const float* bw3 = (const float*)d_in[10];
    const float* g3  = (const float*)d_in[11];
    const float* b3  = (const float*)d_in[12];
    float* out = (float*)d_out;

    float* cat  = (float*)d_ws;                       // [4][256][HW] 64MB
    float* h2   = cat + (long)4 * 256 * HW;           // [4][128][HW] 32MB
    float* sums = h2 + (long)4 * 128 * HW;            // 256 floats
    float* mu   = sums + 256;                         // 128
    float* rstd = mu + 128;                           // 128

    const long catN = 256L * HW, hN = 128L * HW, xN = 512L * HW;

    // scale1: 1x1 conv -> GN -> ReLU  (xd into cat ch 0..127)
    conv1x1_kernel<512><<<dim3(256, 1, 4), 256, 0, stream>>>(x, w1, nullptr, cat, xN, catN);
    hipMemsetAsync(sums, 0, 256 * sizeof(float), stream);
    gn_stats_kernel<<<dim3(128, 4), 256, 0, stream>>>(cat, sums, catN, 4, 32, 16384);
    gn_final_kernel<<<1, 128, 0, stream>>>(sums, mu, rstd, 1.f / 65536.f);
    gn_apply_kernel<<<dim3(16, 128, 4), 256, 0, stream>>>(cat, mu, rstd, g1, b1, catN, 4, 32);

    // cata: 3x3 logits + softmax + unfold-weighted sum (out1 into cat ch 128..255)
    cata_kernel<<<dim3(64, 4), 256, 0, stream>>>(cat, wc);

    // scale2: 1x1 conv on cat -> GN -> ReLU
    conv1x1_kernel<256><<<dim3(256, 1, 4), 256, 0, stream>>>(cat, w2, bw2, h2, catN, hN);
    hipMemsetAsync(sums, 0, 256 * sizeof(float), stream);
    gn_stats_kernel<<<dim3(128, 4), 256, 0, stream>>>(h2, sums, hN, 4, 32, 16384);
    gn_final_kernel<<<1, 128, 0, stream>>>(sums, mu, rstd, 1.f / 65536.f);
    gn_apply_kernel<<<dim3(16, 128, 4), 256, 0, stream>>>(h2, mu, rstd, g2, b2, hN, 4, 32);

    // scale3: 1x1 conv -> GN -> ReLU -> + x   (y3 in d_out, finished in place)
    conv1x1_kernel<128><<<dim3(256, 4, 4), 256, 0, stream>>>(h2, w3, bw3, out, hN, xN);
    hipMemsetAsync(sums, 0, 256 * sizeof(float), stream);
    gn_stats_kernel<<<dim3(128, 16), 256, 0, stream>>>(out, sums, xN, 16, 32, 16384);
    gn_final_kernel<<<1, 128, 0, stream>>>(sums, mu, rstd, 1.f / 262144.f);
    gn_final_apply_kernel<<<dim3(16, 512, 4), 256, 0, stream>>>(out, x, mu, rstd, g3, b3, xN, 16, 32);
}

// Round 2
// 381.311 us; speedup vs baseline: 1.5819x; 1.5819x over previous
//
#include <hip/hip_runtime.h>
#include <math.h>

#define HW 16384
#define W_ 128

typedef __bf16 bf16x8 __attribute__((ext_vector_type(8)));
typedef float f32x4 __attribute__((ext_vector_type(4)));

__device__ __forceinline__ ushort f2bf(float f) {
    uint u = __builtin_bit_cast(uint, f);
    u += 0x7FFFu + ((u >> 16) & 1u);   // round-to-nearest-even
    return (ushort)(u >> 16);
}

union FragU { ushort4 h[2]; bf16x8 v; };

// ---------------------------------------------------------------------------
// 1x1 conv as bf16-MFMA GEMM: out[n][o][p] = bias[o] + sum_c w[o][c]*in[n][c][p]
// block tile 128 o x 128 p, 4 waves (2x2), wave tile 64x64 = 4x4 frags 16x16,
// K-step 32. A_s[o][k] staged from w (coalesced), B_s[p][k] transpose-staged.
// ---------------------------------------------------------------------------
template<int IC>
__global__ __launch_bounds__(256) void conv1x1_mfma(
    const float* __restrict__ in, const float* __restrict__ w,
    const float* __restrict__ bias, float* __restrict__ out,
    long in_nstride, long out_nstride)
{
    __shared__ ushort A_s[128][36];
    __shared__ ushort B_s[128][36];
    const int tid = threadIdx.x;
    const int lane = tid & 63;
    const int wave = tid >> 6;
    const int woM = (wave >> 1) << 6;   // wave o-offset: 0 / 64
    const int wpN = (wave & 1) << 6;    // wave p-offset: 0 / 64
    const int lr = lane & 15;           // row-in-fragment
    const int kg = (lane >> 4) << 2;    // k-group base: 0,4,8,12
    const int n = blockIdx.z;
    const int obase = blockIdx.y << 7;
    const int pbase = blockIdx.x << 7;
    const float* inn = in + (long)n * in_nstride;

    f32x4 acc[4][4] = {};

    for (int c0 = 0; c0 < IC; c0 += 32) {
        // stage A: w[obase..+127][c0..+31] -> A_s[o][k]  (bf16)
#pragma unroll
        for (int r = 0; r < 4; ++r) {
            int idx4 = (r << 8) + tid;           // quad index 0..1023
            int o = idx4 >> 3, kq = idx4 & 7;
            float4 wv = *(const float4*)&w[(long)(obase + o) * IC + c0 + (kq << 2)];
            ushort4 hb;
            hb.x = f2bf(wv.x); hb.y = f2bf(wv.y); hb.z = f2bf(wv.z); hb.w = f2bf(wv.w);
            *(ushort4*)&A_s[o][kq << 2] = hb;
        }
        // stage B: in[c0..+31][pbase..+127] -> B_s[p][c]  (transpose, bf16)
#pragma unroll
        for (int r = 0; r < 16; ++r) {
            int idx = (r << 8) + tid;            // 0..4095
            int c = idx >> 7, p = idx & 127;
            B_s[p][c] = f2bf(inn[(long)(c0 + c) * HW + pbase + p]);
        }
        __syncthreads();

        FragU af[4], bfr[4];
#pragma unroll
        for (int mo = 0; mo < 4; ++mo) {
            const ushort* base = &A_s[woM + (mo << 4) + lr][0];
            af[mo].h[0] = *(const ushort4*)(base + kg);
            af[mo].h[1] = *(const ushort4*)(base + 16 + kg);
        }
#pragma unroll
        for (int po = 0; po < 4; ++po) {
            const ushort* base = &B_s[wpN + (po << 4) + lr][0];
            bfr[po].h[0] = *(const ushort4*)(base + kg);
            bfr[po].h[1] = *(const ushort4*)(base + 16 + kg);
        }
#pragma unroll
        for (int mo = 0; mo < 4; ++mo)
#pragma unroll
            for (int po = 0; po < 4; ++po)
                acc[mo][po] = __builtin_amdgcn_mfma_f32_16x16x32_bf16(
                    af[mo].v, bfr[po].v, acc[mo][po], 0, 0, 0);
        __syncthreads();
    }

    float* outn = out + (long)n * out_nstride;
#pragma unroll
    for (int mo = 0; mo < 4; ++mo) {
        int orow0 = obase + woM + (mo << 4) + ((lane >> 4) << 2);
#pragma unroll
        for (int po = 0; po < 4; ++po) {
            int p = pbase + wpN + (po << 4) + (lane & 15);
#pragma unroll
            for (int r = 0; r < 4; ++r) {
                int o = orow0 + r;
                float b = bias ? bias[o] : 0.f;
                outn[(long)o * HW + p] = acc[mo][po][r] + b;
            }
        }
    }
}

// ---------------------------------------------------------------------------
// GroupNorm stats: per (n,g) accumulate sum / sumsq with split blocks + atomics
// ---------------------------------------------------------------------------
__global__ __launch_bounds__(256) void gn_stats_kernel(
    const float* __restrict__ y, float* __restrict__ sums,
    long nstride, int CG, int G, int split_elems)
{
    const int ng = blockIdx.x;
    const int n = ng / G, g = ng % G;
    const float* base = y + (long)n * nstride + (long)g * CG * HW
                        + (long)blockIdx.y * split_elems;
    float s = 0.f, ss = 0.f;
    for (int i = threadIdx.x * 4; i < split_elems; i += 1024) {
        float4 v = *(const float4*)&base[i];
        s  += v.x + v.y + v.z + v.w;
        ss += v.x * v.x + v.y * v.y + v.z * v.z + v.w * v.w;
    }
#pragma unroll
    for (int off = 32; off > 0; off >>= 1) {
        s  += __shfl_down(s, off, 64);
        ss += __shfl_down(ss, off, 64);
    }
    __shared__ float rs[4], rss[4];
    int wave = threadIdx.x >> 6, lane = threadIdx.x & 63;
    if (lane == 0) { rs[wave] = s; rss[wave] = ss; }
    __syncthreads();
    if (threadIdx.x == 0) {
        atomicAdd(&sums[2 * ng],     rs[0] + rs[1] + rs[2] + rs[3]);
        atomicAdd(&sums[2 * ng + 1], rss[0] + rss[1] + rss[2] + rss[3]);
    }
}

__global__ void gn_final_kernel(const float* __restrict__ sums,
                                float* __restrict__ mu, float* __restrict__ rstd,
                                float cinv)
{
    int i = threadIdx.x;
    if (i < 128) {
        float m = sums[2 * i] * cinv;
        float var = sums[2 * i + 1] * cinv - m * m;
        mu[i] = m;
        rstd[i] = rsqrtf(var + 1e-5f);
    }
}

__global__ __launch_bounds__(256) void gn_apply_kernel(
    float* __restrict__ y, const float* __restrict__ mu, const float* __restrict__ rstd,
    const float* __restrict__ gamma, const float* __restrict__ beta,
    long nstride, int CG, int G)
{
    const int n = blockIdx.z, c = blockIdx.y;
    const int ng = n * G + c / CG;
    const float a = rstd[ng] * gamma[c];
    const float b = beta[c] - mu[ng] * a;
    float* p = y + (long)n * nstride + (long)c * HW + (blockIdx.x << 10) + (threadIdx.x << 2);
    float4 v = *(const float4*)p;
    v.x = fmaxf(v.x * a + b, 0.f);
    v.y = fmaxf(v.y * a + b, 0.f);
    v.z = fmaxf(v.z * a + b, 0.f);
    v.w = fmaxf(v.w * a + b, 0.f);
    *(float4*)p = v;
}

__global__ __launch_bounds__(256) void gn_final_apply_kernel(
    float* __restrict__ y, const float* __restrict__ x,
    const float* __restrict__ mu, const float* __restrict__ rstd,
    const float* __restrict__ gamma, const float* __restrict__ beta,
    long nstride, int CG, int G)
{
    const int n = blockIdx.z, c = blockIdx.y;
    const int ng = n * G + c / CG;
    const float a = rstd[ng] * gamma[c];
    const float b = beta[c] - mu[ng] * a;
    long off = (long)n * nstride + (long)c * HW + (blockIdx.x << 10) + (threadIdx.x << 2);
    float4 v = *(const float4*)&y[off];
    float4 xv = *(const float4*)&x[off];
    v.x = fmaxf(v.x * a + b, 0.f) + xv.x;
    v.y = fmaxf(v.y * a + b, 0.f) + xv.y;
    v.z = fmaxf(v.z * a + b, 0.f) + xv.z;
    v.w = fmaxf(v.w * a + b, 0.f) + xv.w;
    *(float4*)&y[off] = v;
}

// ---------------------------------------------------------------------------
// cata pass 1: 3x3 conv -> 9 logits per pixel, channel-chunked (32 ch/block),
// halo tile in LDS, atomicAdd into logits[n][9][HW] (pre-zeroed).
// grid (32 row-tiles, 4 n, 4 chunks), block 256, 2 px/thread (tile 4x128).
// ---------------------------------------------------------------------------
#define RT 4
__global__ __launch_bounds__(256) void cata_logits_kernel(
    const float* __restrict__ xd, const float* __restrict__ wc,
    float* __restrict__ logits)
{
    __shared__ float wcs[9 * 32 * 9];          // 10368 B
    __shared__ float xs[RT + 2][130];          // 3120 B
    const int tid = threadIdx.x;
    const int r0 = blockIdx.x * RT;
    const int n = blockIdx.y;
    const int c0 = blockIdx.z << 5;
    for (int i = tid; i < 9 * 32 * 9; i += 256) {
        int k = i / 288, rem = i % 288;
        wcs[i] = wc[k * 1152 + c0 * 9 + rem];
    }
    const float* xn = xd + (long)n * 256 * HW;
    float lg[2][9] = {};
    for (int cc = 0; cc < 32; ++cc) {
        __syncthreads();
        const float* xc = xn + (long)(c0 + cc) * HW;
        for (int i = tid; i < (RT + 2) * 130; i += 256) {
            int rr = i / 130, cl = i % 130;
            int gr = r0 - 1 + rr, gc = cl - 1;
            xs[rr][cl] = (gr >= 0 && gr < 128 && gc >= 0 && gc < 128)
                         ? xc[gr * W_ + gc] : 0.f;
        }
        __syncthreads();
#pragma unroll
        for (int q = 0; q < 2; ++q) {
            int pl = (q << 8) + tid;
            int lrow = pl >> 7, w = pl & 127;
            float nb[9];
#pragma unroll
            for (int di = 0; di < 3; ++di)
#pragma unroll
                for (int dj = 0; dj < 3; ++dj)
                    nb[di * 3 + dj] = xs[lrow + di][w + dj];
#pragma unroll
            for (int k = 0; k < 9; ++k) {
                const float* wk = &wcs[(k * 32 + cc) * 9];
                float s = lg[q][k];
#pragma unroll
                for (int t = 0; t < 9; ++t) s += wk[t] * nb[t];
                lg[q][k] = s;
            }
        }
    }
    float* lgn = logits + (long)n * 9 * HW + r0 * W_;
#pragma unroll
    for (int q = 0; q < 2; ++q)
#pragma unroll
        for (int k = 0; k < 9; ++k)
            atomicAdd(&lgn[(long)k * HW + (q << 8) + tid], lg[q][k]);
}

// ---------------------------------------------------------------------------
// cata pass 2: softmax over 9 logits (registers) + weighted 3x3 sum.
// out1 written to cat channels 128..255. Same grid as pass 1.
// ---------------------------------------------------------------------------
__global__ __launch_bounds__(256) void cata_wsum_kernel(
    float* __restrict__ cat, const float* __restrict__ logits)
{
    __shared__ float xs[RT + 2][130];
    const int tid = threadIdx.x;
    const int r0 = blockIdx.x * RT;
    const int n = blockIdx.y;
    const int c0 = blockIdx.z << 5;
    const float* lgn = logits + (long)n * 9 * HW + r0 * W_;
    float filt[2][9];
#pragma unroll
    for (int q = 0; q < 2; ++q) {
        float v[9], m = -1e30f;
#pragma unroll
        for (int k = 0; k < 9; ++k) {
            v[k] = lgn[(long)k * HW + (q << 8) + tid];
            m = fmaxf(m, v[k]);
        }
        float s = 0.f;
#pragma unroll
        for (int k = 0; k < 9; ++k) { v[k] = __expf(v[k] - m); s += v[k]; }
        float inv = 1.f / s;
#pragma unroll
        for (int k = 0; k < 9; ++k) filt[q][k] = v[k] * inv;
    }
    const float* xn = cat + (long)n * 256 * HW;
    float* o1 = cat + (long)n * 256 * HW + 128L * HW + r0 * W_;
    for (int cc = 0; cc < 32; ++cc) {
        __syncthreads();
        const float* xc = xn + (long)(c0 + cc) * HW;
        for (int i = tid; i < (RT + 2) * 130; i += 256) {
            int rr = i / 130, cl = i % 130;
            int gr = r0 - 1 + rr, gc = cl - 1;
            xs[rr][cl] = (gr >= 0 && gr < 128 && gc >= 0 && gc < 128)
                         ? xc[gr * W_ + gc] : 0.f;
        }
        __syncthreads();
#pragma unroll
        for (int q = 0; q < 2; ++q) {
            int pl = (q << 8) + tid;
            int lrow = pl >> 7, w = pl & 127;
            float s = 0.f;
#pragma unroll
            for (int di = 0; di < 3; ++di)
#pragma unroll
                for (int dj = 0; dj < 3; ++dj)
                    s += filt[q][di * 3 + dj] * xs[lrow + di][w + dj];
            o1[(long)(c0 + cc) * HW + pl] = s;
        }
    }
}

// ---------------------------------------------------------------------------
extern "C" void kernel_launch(void* const* d_in, const int* in_sizes, int n_in,
                              void* d_out, int out_size, void* d_ws, size_t ws_size,
                              hipStream_t stream)
{
    const float* x   = (const float*)d_in[0];
    const float* w1  = (const float*)d_in[1];
    const float* g1  = (const float*)d_in[2];
    const float* b1  = (const float*)d_in[3];
    const float* wc  = (const float*)d_in[4];
    const float* w2  = (const float*)d_in[5];
    const float* bw2 = (const float*)d_in[6];
    const float* g2  = (const float*)d_in[7];
    const float* b2  = (const float*)d_in[8];
    const float* w3  = (const float*)d_in[9];
    const float* bw3 = (const float*)d_in[10];
    const float* g3  = (const float*)d_in[11];
    const float* b3  = (const float*)d_in[12];
    float* out = (float*)d_out;

    float* cat    = (float*)d_ws;                     // [4][256][HW] 64MB
    float* h2     = cat + (long)4 * 256 * HW;         // [4][128][HW] 32MB
    float* sums   = h2 + (long)4 * 128 * HW;          // 256
    float* mu     = sums + 256;                       // 128
    float* rstd   = mu + 128;                         // 128
    float* logits = rstd + 128;                       // [4][9][HW] 2.36MB

    const long catN = 256L * HW, hN = 128L * HW, xN = 512L * HW;

    // scale1: 1x1 conv (bf16 MFMA) -> GN -> ReLU  (xd into cat ch 0..127)
    conv1x1_mfma<512><<<dim3(128, 1, 4), 256, 0, stream>>>(x, w1, nullptr, cat, xN, catN);
    hipMemsetAsync(sums, 0, 256 * sizeof(float), stream);
    gn_stats_kernel<<<dim3(128, 4), 256, 0, stream>>>(cat, sums, catN, 4, 32, 16384);
    gn_final_kernel<<<1, 128, 0, stream>>>(sums, mu, rstd, 1.f / 65536.f);
    gn_apply_kernel<<<dim3(16, 128, 4), 256, 0, stream>>>(cat, mu, rstd, g1, b1, catN, 4, 32);

    // cata: logits (atomic, channel-chunked) -> softmax+wsum
    hipMemsetAsync(logits, 0, (size_t)4 * 9 * HW * sizeof(float), stream);
    cata_logits_kernel<<<dim3(32, 4, 4), 256, 0, stream>>>(cat, wc, logits);
    cata_wsum_kernel<<<dim3(32, 4, 4), 256, 0, stream>>>(cat, logits);

    // scale2: 1x1 conv on cat -> GN -> ReLU
    conv1x1_mfma<256><<<dim3(128, 1, 4), 256, 0, stream>>>(cat, w2, bw2, h2, catN, hN);
    hipMemsetAsync(sums, 0, 256 * sizeof(float), stream);
    gn_stats_kernel<<<dim3(128, 4), 256, 0, stream>>>(h2, sums, hN, 4, 32, 16384);
    gn_final_kernel<<<1, 128, 0, stream>>>(sums, mu, rstd, 1.f / 65536.f);
    gn_apply_kernel<<<dim3(16, 128, 4), 256, 0, stream>>>(h2, mu, rstd, g2, b2, hN, 4, 32);

    // scale3: 1x1 conv -> GN -> ReLU -> + x
    conv1x1_mfma<128><<<dim3(128, 4, 4), 256, 0, stream>>>(h2, w3, bw3, out, hN, xN);
    hipMemsetAsync(sums, 0, 256 * sizeof(float), stream);
    gn_stats_kernel<<<dim3(128, 16), 256, 0, stream>>>(out, sums, xN, 16, 32, 16384);
    gn_final_kernel<<<1, 128, 0, stream>>>(sums, mu, rstd, 1.f / 262144.f);
    gn_final_apply_kernel<<<dim3(16, 512, 4), 256, 0, stream>>>(out, x, mu, rstd, g3, b3, xN, 16, 32);
}